// Round 1
// 250.300 us; speedup vs baseline: 1.0083x; 1.0083x over previous
//
#include <hip/hip_runtime.h>

#define LAMBDA_G 1.938f
#define LAMBDA_F 1.912f
#define EPSV     1e-8f

constexpr int B = 8, N = 1000, C = 4000, D = 128;
constexpr int S = 25, RPB = 40, RPT = 5;   // ctx slabs: 25 slabs x 40 rows; 8 row-groups x 5 rows/thread
constexpr int Q = 4;                       // points per reward block

typedef float f4 __attribute__((ext_vector_type(4)));

__device__ __forceinline__ float waveReduceSum(float v) {
#pragma unroll
    for (int off = 32; off > 0; off >>= 1)
        v += __shfl_down(v, off, 64);
    return v;
}

__device__ __forceinline__ float rcpf(float x) { return __builtin_amdgcn_rcpf(x); }

// One block per QUAD of points (same batch): u0/pop loaded once per block and
// applied to up to four u-rows (halves L2 amortization traffic vs pair version,
// doubles independent nontemporal loads in flight). u rows streamed
// nontemporally (read-once). Inactive rows (cc>=2) read nothing.
__global__ __launch_bounds__(256) void reward_quad_kernel(
    const float* __restrict__ u_reg, const float* __restrict__ u_food,
    const float* __restrict__ u0,    const float* __restrict__ pop,
    const int*   __restrict__ chosen,
    const float* __restrict__ dd_reg, const float* __restrict__ dd_food,
    const float* __restrict__ fcp,   float* __restrict__ reward)
{
    const int blk = blockIdx.x;              // 0 .. B*N/Q-1
    const int b   = blk / (N / Q);
    const int bj0 = b * N + (blk % (N / Q)) * Q;
    const int t   = threadIdx.x;

    int  cc[Q];
    bool act[Q];
    bool any = false;
#pragma unroll
    for (int k = 0; k < Q; ++k) {            // compile-time k -> stays in registers
        cc[k]  = chosen[bj0 + k];
        act[k] = cc[k] < 2;
        any   |= act[k];
    }
    if (!any) {                              // all four rewards provably zero (p ~ 1.2%)
        if (t < Q) reward[bj0 + t] = 0.0f;
        return;
    }

    const f4* __restrict__ u4[Q];
#pragma unroll
    for (int k = 0; k < Q; ++k)
        u4[k] = (const f4*)((cc[k] == 0 ? u_reg : u_food) + (size_t)(bj0 + k) * C);
    const f4* __restrict__ u04 = (const f4*)(u0  + (size_t)b * C);
    const f4* __restrict__ p4  = (const f4*)(pop + (size_t)b * C);

    float acc[Q] = {0.f, 0.f, 0.f, 0.f};

    auto body = [&](int c4) {
        const f4 ov = u04[c4];
        const f4 pv = p4[c4];
#pragma unroll
        for (int k = 0; k < Q; ++k) {
            if (act[k]) {                    // block-uniform branch, no divergence
                const f4 uv = __builtin_nontemporal_load(u4[k] + c4);
                acc[k] += pv.x * uv.x * rcpf(ov.x + uv.x + EPSV);
                acc[k] += pv.y * uv.y * rcpf(ov.y + uv.y + EPSV);
                acc[k] += pv.z * uv.z * rcpf(ov.z + uv.z + EPSV);
                acc[k] += pv.w * uv.w * rcpf(ov.w + uv.w + EPSV);
            }
        }
    };

    // C/4 = 1000 = 3*256 + 232: peel into compile-time 3x unroll + tail so the
    // compiler can hoist all independent loads per iteration.
    int c4 = t;
#pragma unroll
    for (int it = 0; it < 3; ++it, c4 += 256) body(c4);
    if (c4 < C / 4) body(c4);

    __shared__ float red[Q][4];
    float ws[Q];
#pragma unroll
    for (int k = 0; k < Q; ++k) ws[k] = waveReduceSum(acc[k]);
    if ((t & 63) == 0) {
#pragma unroll
        for (int k = 0; k < Q; ++k) red[k][t >> 6] = ws[k];
    }
    __syncthreads();
    if (t < Q) {
        const int  bj  = bj0 + t;
        const int  ccv = chosen[bj];         // reload (cheap L1 hit): avoids
        const bool a   = ccv < 2;            // runtime-indexed register array -> scratch
        const float s  = red[t][0] + red[t][1] + red[t][2] + red[t][3];
        const float revenue = (ccv == 0 ? LAMBDA_G : LAMBDA_F) * s;   // 0 if inactive
        const float ddv = a ? (ccv == 0 ? dd_reg[bj] : dd_food[bj]) : 0.0f;
        const float fx  = a ? fcp[bj] : 0.0f;
        const float adv = 0.11f * revenue - 3.5e-3f * ddv - fx;
        reward[bj] = fmaxf(adv, 0.0f) * 0.01f;
    }
}

// B*S blocks: exp-weighted partial context over a 40-row slab + partial sum(exp).
// reward in [0, ~9] so exp() needs no max-subtraction (softmax shift-invariant).
__global__ __launch_bounds__(256) void ctx_partial_kernel(
    const float* __restrict__ reward, const float* __restrict__ emb,
    float* __restrict__ partials, float* __restrict__ psum)
{
    const int blk = blockIdx.x;
    const int b = blk / S, s = blk % S;
    const int t = threadIdx.x;
    const int d4 = t & 31;       // which float4 along D (32*4 = 128)
    const int rg = t >> 5;       // row group 0..7

    const float* __restrict__ eb = emb + ((size_t)b * N + s * RPB) * D;
    const float* __restrict__ rv = reward + b * N + s * RPB;

    __shared__ float esum[RPB];

    f4 acc = {0.f, 0.f, 0.f, 0.f};
#pragma unroll
    for (int k = 0; k < RPT; ++k) {
        const int j = rg * RPT + k;
        const float w = __expf(rv[j]);
        if (d4 == 0) esum[j] = w;
        const f4 v = ((const f4*)(eb + (size_t)j * D))[d4];
        acc += v * w;
    }

    __shared__ float lds[8][D];
    *(f4*)&lds[rg][d4 * 4] = acc;
    __syncthreads();
    if (t < D) {
        float sum = 0.f;
#pragma unroll
        for (int g = 0; g < 8; ++g) sum += lds[g][t];
        partials[((size_t)b * S + s) * D + t] = sum;
    }
    if (t == 0) {
        float se = 0.f;
#pragma unroll
        for (int j = 0; j < RPB; ++j) se += esum[j];
        psum[b * S + s] = se;
    }
}

// 8 blocks: reduce S partials + sumexp -> ctx, then out = ctx @ W^T + bias
__global__ __launch_bounds__(128) void finalize_kernel(
    const float* __restrict__ partials, const float* __restrict__ psum,
    const float* __restrict__ Wm, const float* __restrict__ bias,
    float* __restrict__ out)
{
    const int b = blockIdx.x;
    const int t = threadIdx.x;

    __shared__ float ctx[D];
    float sum = 0.f, se = 0.f;
#pragma unroll 5
    for (int si = 0; si < S; ++si) {
        sum += partials[((size_t)b * S + si) * D + t];
        se  += psum[b * S + si];
    }
    ctx[t] = sum * rcpf(se);
    __syncthreads();

    const float* __restrict__ wr = Wm + t * D;
    float a = bias[t];
#pragma unroll 8
    for (int dd = 0; dd < D; ++dd) a += ctx[dd] * wr[dd];
    out[b * D + t] = a;
}

extern "C" void kernel_launch(void* const* d_in, const int* in_sizes, int n_in,
                              void* d_out, int out_size, void* d_ws, size_t ws_size,
                              hipStream_t stream) {
    const float* emb     = (const float*)d_in[0];   // [B,N,D]
    const int*   chosen  = (const int*)  d_in[1];   // [B,N]
    const float* u_reg   = (const float*)d_in[2];   // [B,N,C]
    const float* u_food  = (const float*)d_in[3];   // [B,N,C]
    const float* u0      = (const float*)d_in[4];   // [B,C]
    const float* pop     = (const float*)d_in[5];   // [B,C,1]
    const float* dd_reg  = (const float*)d_in[6];   // [B,N,1]
    const float* dd_food = (const float*)d_in[7];   // [B,N,1]
    const float* fcp     = (const float*)d_in[8];   // [B,1,N]
    const float* Wm      = (const float*)d_in[9];   // [D,D]
    const float* bias    = (const float*)d_in[10];  // [D]
    float* out = (float*)d_out;

    float* reward   = (float*)d_ws;                 // B*N
    float* partials = reward + B * N;               // B*S*D
    float* psum     = partials + B * S * D;         // B*S

    reward_quad_kernel<<<B * N / Q, 256, 0, stream>>>(u_reg, u_food, u0, pop, chosen,
                                                      dd_reg, dd_food, fcp, reward);
    ctx_partial_kernel<<<B * S, 256, 0, stream>>>(reward, emb, partials, psum);
    finalize_kernel<<<B, 128, 0, stream>>>(partials, psum, Wm, bias, out);
}